// Round 1
// baseline (15279.286 us; speedup 1.0000x reference)
//
#include <hip/hip_runtime.h>

// ---------------------------------------------------------------------------
// RMT layer: B=16 chains x NM=64 sequential steps.
// R1: per-step kernels fused 4 -> 2 via last-finisher tickets
//     (gemm1+attn, gemm2+ln2), mask early-exit, single in-place mem buffer.
// ---------------------------------------------------------------------------

typedef __attribute__((ext_vector_type(8))) _Float16 f16x8;
typedef __attribute__((ext_vector_type(4))) _Float16 f16x4;
typedef __attribute__((ext_vector_type(8))) short    s16x8;
typedef __attribute__((ext_vector_type(4))) float    f32x4;

#define NB   16
#define NMs  64
#define MBs  64
#define Dm   1024
#define NHh  16
#define NKVh 8
#define HDd  64
#define MEMm 64
#define Sq   128

// ---------------- static device scratch -------------------------------------
__device__ __align__(16) _Float16      g_W1t[2048 * 1024];   // [n][k]: 0..1023 q, 1024..1535 k, 1536..2047 v
__device__ __align__(16) _Float16      g_Wot[1024 * 1024];   // wo^T [n][k]
__device__ __align__(16) float         g_rc[128 * 32];
__device__ __align__(16) float         g_rs[128 * 32];
__device__                unsigned char g_mask[NB * NMs];
__device__ __align__(16) _Float16      g_hx[(size_t)NB * NMs * MBs * Dm]; // LN'd x rows, f16
__device__ __align__(16) _Float16      g_hmem[NB * MEMm * Dm];            // LN'd mem rows, f16
__device__ __align__(16) float         g_mem[NB * MEMm * Dm];             // fp32 mem (in-place)
__device__ __align__(16) unsigned short g_qb[NB * NHh * 64 * 64];     // [b][h][m][d]  bf16
__device__ __align__(16) unsigned short g_kb[NB * NKVh * 128 * 64];   // [b][kvh][pos][d] bf16
__device__ __align__(16) unsigned short g_vt[NB * NKVh * 64 * 128];   // [b][kvh][d][pos] bf16
__device__ __align__(16) _Float16      g_enc[NB * 64 * Dm];           // attention out, f16
__device__ __align__(16) float         g_outp[NB * 64 * Dm];          // enc @ wo, fp32
__device__ unsigned int g_tk1[NB * NHh];   // per-(b,head) attn tickets (5 contributors)
__device__ unsigned int g_tk2[NB];         // per-batch ln tickets (16 contributors)

// ---------------- helpers ---------------------------------------------------
__device__ __forceinline__ unsigned short f2bf(float x) {
    union { float f; unsigned u; } v; v.f = x;
    unsigned u = v.u;
    return (unsigned short)((u + 0x7fffu + ((u >> 16) & 1u)) >> 16);  // RNE
}
__device__ __forceinline__ float bf2f(unsigned short h) {
    union { unsigned u; float f; } v; v.u = ((unsigned)h) << 16; return v.f;
}

__device__ __forceinline__ void block_stats(float s, float ss, float eps,
                                            float* mean, float* rstd) {
    for (int off = 32; off > 0; off >>= 1) {
        s  += __shfl_down(s, off);
        ss += __shfl_down(ss, off);
    }
    __shared__ float red[8];
    int wid = threadIdx.x >> 6, lane = threadIdx.x & 63;
    __syncthreads();
    if (lane == 0) { red[wid] = s; red[4 + wid] = ss; }
    __syncthreads();
    float ts  = red[0] + red[1] + red[2] + red[3];
    float tss = red[4] + red[5] + red[6] + red[7];
    float m   = ts * (1.0f / 1024.0f);
    float var = tss * (1.0f / 1024.0f) - m * m;
    *mean = m;
    *rstd = rsqrtf(var + eps);
}

// ---------------- init kernels ----------------------------------------------
__global__ void k_transpose(const float* __restrict__ in, int ncols, int dsel) {
    _Float16* out = (dsel == 0) ? g_W1t
                  : (dsel == 1) ? (g_W1t + 1024 * 1024)
                  : (dsel == 2) ? (g_W1t + 1536 * 1024)
                                : g_Wot;
    __shared__ float tile[64][65];
    int bk = blockIdx.x, bn = blockIdx.y;
    int c = threadIdx.x & 63, rg = threadIdx.x >> 6;
    int k0 = bk * 64, n0 = bn * 64;
    for (int i = 0; i < 16; i++) {
        int r = rg * 16 + i;
        tile[r][c] = in[(size_t)(k0 + r) * ncols + n0 + c];
    }
    __syncthreads();
    for (int i = 0; i < 16; i++) {
        int r = rg * 16 + i;
        out[(size_t)(n0 + r) * 1024 + k0 + c] = (_Float16)tile[c][r];
    }
}

__global__ void k_rope() {
    int t = threadIdx.x;  // 128 positions
    for (int j = 0; j < 32; j++) {
        double f = pow(10000.0, -(double)j / 32.0);
        double a = (double)t * f;
        g_rc[t * 32 + j] = (float)cos(a);
        g_rs[t * 32 + j] = (float)sin(a);
    }
}

__global__ void k_mask(const unsigned int* __restrict__ ip) {
    __shared__ int byteFmt;
    int t = threadIdx.x;  // 1024
    if (t == 0) byteFmt = 0;
    __syncthreads();
    if (t < 256) {
        unsigned v = ip[t];
        if (!(v == 0u || v == 1u || v == 0x3F800000u)) byteFmt = 1;
    }
    __syncthreads();
    unsigned char m = byteFmt ? (((const unsigned char*)ip)[t] != 0)
                              : (ip[t] != 0u);
    g_mask[t] = m;
}

__global__ void k_ln_hx(const float* __restrict__ x,
                        const float* __restrict__ sc, const float* __restrict__ bi) {
    size_t row = blockIdx.x;
    int t = threadIdx.x;
    float4 v = ((const float4*)(x + row * 1024))[t];
    float mean, rstd;
    block_stats(v.x + v.y + v.z + v.w,
                v.x * v.x + v.y * v.y + v.z * v.z + v.w * v.w, 1e-6f, &mean, &rstd);
    float4 s4 = ((const float4*)sc)[t];
    float4 b4 = ((const float4*)bi)[t];
    f16x4 o;
    o[0] = (_Float16)((v.x - mean) * rstd * s4.x + b4.x);
    o[1] = (_Float16)((v.y - mean) * rstd * s4.y + b4.y);
    o[2] = (_Float16)((v.z - mean) * rstd * s4.z + b4.z);
    o[3] = (_Float16)((v.w - mean) * rstd * s4.w + b4.w);
    *(f16x4*)(g_hx + row * 1024 + t * 4) = o;
}

__global__ void k_ln_init(const float* __restrict__ ms,
                          const float* __restrict__ sc, const float* __restrict__ bi) {
    int b = blockIdx.x >> 6, r = blockIdx.x & 63;
    int t = threadIdx.x;
    float4 v = ((const float4*)(ms + (size_t)r * 1024))[t];
    ((float4*)(g_mem + ((size_t)b * 64 + r) * 1024))[t] = v;
    float mean, rstd;
    block_stats(v.x + v.y + v.z + v.w,
                v.x * v.x + v.y * v.y + v.z * v.z + v.w * v.w, 1e-6f, &mean, &rstd);
    float4 s4 = ((const float4*)sc)[t];
    float4 b4 = ((const float4*)bi)[t];
    f16x4 o;
    o[0] = (_Float16)((v.x - mean) * rstd * s4.x + b4.x);
    o[1] = (_Float16)((v.y - mean) * rstd * s4.y + b4.y);
    o[2] = (_Float16)((v.z - mean) * rstd * s4.z + b4.z);
    o[3] = (_Float16)((v.w - mean) * rstd * s4.w + b4.w);
    *(f16x4*)(g_hmem + ((size_t)b * 64 + r) * 1024 + t * 4) = o;
}

// ---------------- 64x64-tile f16 MFMA GEMM core (K=1024) --------------------
__device__ __forceinline__ void gemm_core(const _Float16* __restrict__ Abase,
                                          const _Float16* __restrict__ Bbase,
                                          _Float16* As, _Float16* Bs,
                                          f32x4 acc[2][2]) {
    int tid = threadIdx.x;
    int w = tid >> 6, l = tid & 63;
    int mo = (w & 1) * 32, no = (w >> 1) * 32;
    int sr = tid >> 2, sk = (tid & 3) * 8;
    int fr = l & 15, fq = (l >> 4) * 8;
    for (int kt = 0; kt < 32; ++kt) {
        f16x8 av = *(const f16x8*)(Abase + (size_t)sr * 1024 + kt * 32 + sk);
        f16x8 bv = *(const f16x8*)(Bbase + (size_t)sr * 1024 + kt * 32 + sk);
        __syncthreads();
        *(f16x8*)&As[sr * 40 + sk] = av;
        *(f16x8*)&Bs[sr * 40 + sk] = bv;
        __syncthreads();
        f16x8 a0 = *(const f16x8*)&As[(mo + fr) * 40 + fq];
        f16x8 a1 = *(const f16x8*)&As[(mo + 16 + fr) * 40 + fq];
        f16x8 b0 = *(const f16x8*)&Bs[(no + fr) * 40 + fq];
        f16x8 b1 = *(const f16x8*)&Bs[(no + 16 + fr) * 40 + fq];
        acc[0][0] = __builtin_amdgcn_mfma_f32_16x16x32_f16(a0, b0, acc[0][0], 0, 0, 0);
        acc[0][1] = __builtin_amdgcn_mfma_f32_16x16x32_f16(a0, b1, acc[0][1], 0, 0, 0);
        acc[1][0] = __builtin_amdgcn_mfma_f32_16x16x32_f16(a1, b0, acc[1][0], 0, 0, 0);
        acc[1][1] = __builtin_amdgcn_mfma_f32_16x16x32_f16(a1, b1, acc[1][1], 0, 0, 0);
    }
}

// ---------------- attention for one head (wave-local LDS, no barriers) ------
__device__ void attn_one(int b, int h, unsigned short* att_s) {
    int kvh = h >> 1;
    int tid = threadIdx.x, w = tid >> 6, l = tid & 63;
    int fr = l & 15, fq = (l >> 4) * 8;
    const unsigned short* qp = g_qb + ((size_t)b * 16 + h) * 64 * 64;
    const unsigned short* kp = g_kb + ((size_t)b * 8 + kvh) * 128 * 64;
    const unsigned short* vp = g_vt + ((size_t)b * 8 + kvh) * 64 * 128;

    s16x8 aq0 = *(const s16x8*)(qp + (w * 16 + fr) * 64 + fq);
    s16x8 aq1 = *(const s16x8*)(qp + (w * 16 + fr) * 64 + 32 + fq);
    f32x4 sc[8];
    for (int nt = 0; nt < 8; nt++) {
        sc[nt] = (f32x4){0.f, 0.f, 0.f, 0.f};
        s16x8 kb0 = *(const s16x8*)(kp + (nt * 16 + fr) * 64 + fq);
        s16x8 kb1 = *(const s16x8*)(kp + (nt * 16 + fr) * 64 + 32 + fq);
        sc[nt] = __builtin_amdgcn_mfma_f32_16x16x32_bf16(aq0, kb0, sc[nt], 0, 0, 0);
        sc[nt] = __builtin_amdgcn_mfma_f32_16x16x32_bf16(aq1, kb1, sc[nt], 0, 0, 0);
    }
    float lv[8][4];
    for (int nt = 0; nt < 8; nt++)
        for (int r = 0; r < 4; r++)
            lv[nt][r] = bf2f(f2bf(sc[nt][r])) * 0.125f;

    int quad = l >> 4;
    for (int r = 0; r < 4; r++) {
        float mx = -1e30f;
        for (int nt = 0; nt < 8; nt++) mx = fmaxf(mx, lv[nt][r]);
        for (int off = 1; off < 16; off <<= 1) mx = fmaxf(mx, __shfl_xor(mx, off));
        float sm = 0.f;
        for (int nt = 0; nt < 8; nt++) { lv[nt][r] = expf(lv[nt][r] - mx); sm += lv[nt][r]; }
        for (int off = 1; off < 16; off <<= 1) sm += __shfl_xor(sm, off);
        float inv = 1.0f / sm;
        int row = w * 16 + quad * 4 + r;
        for (int nt = 0; nt < 8; nt++)
            att_s[row * 136 + nt * 16 + fr] = f2bf(lv[nt][r] * inv);
    }
    f32x4 o[4];
    for (int nt = 0; nt < 4; nt++) o[nt] = (f32x4){0.f, 0.f, 0.f, 0.f};
    for (int kt = 0; kt < 4; kt++) {
        s16x8 a = *(const s16x8*)&att_s[(w * 16 + fr) * 136 + kt * 32 + fq];
        for (int nt = 0; nt < 4; nt++) {
            s16x8 bv = *(const s16x8*)(vp + (nt * 16 + fr) * 128 + kt * 32 + fq);
            o[nt] = __builtin_amdgcn_mfma_f32_16x16x32_bf16(a, bv, o[nt], 0, 0, 0);
        }
    }
    for (int nt = 0; nt < 4; nt++)
        for (int r = 0; r < 4; r++) {
            int m = w * 16 + quad * 4 + r;
            int d = nt * 16 + fr;
            g_enc[((size_t)b * 64 + m) * 1024 + h * 64 + d] =
                (_Float16)bf2f(f2bf(o[nt][r]));
        }
}

// ---------------- step kernel 1: QKV GEMM + RoPE + fused attention ----------
// grid = 16*48 = 768, block 256.
// tickets: per (b,head). contributors to head h (kvh=h/2): q tile (1),
// k tiles mtile0+mtile1 (2), v tiles mtile0+mtile1 (2) -> 5, winner old==4.
__launch_bounds__(256)
__global__ void k_step1(int s) {
    int bid = blockIdx.x;
    int b = bid / 48, t48 = bid % 48;
    if (!g_mask[b * 64 + s]) return;                 // masked step: entire batch skipped
    int mtile = (t48 < 16) ? 0 : 1;
    int ntile = (t48 < 16) ? (16 + t48) : (t48 - 16);
    const _Float16* Abase = (mtile == 0)
        ? (g_hx + ((size_t)(b * NMs + s) * 64) * 1024)
        : (g_hmem + (size_t)b * 64 * 1024);
    const _Float16* Bbase = g_W1t + (size_t)ntile * 64 * 1024;
    __shared__ __align__(16) unsigned char smem[64 * 136 * 2];  // union: As|Bs (10240) / att_s (17408)
    _Float16* As = (_Float16*)smem;
    _Float16* Bs = (_Float16*)(smem + 64 * 40 * 2);
    f32x4 acc[2][2] = {};
    gemm_core(Abase, Bbase, As, Bs, acc);

    int tid = threadIdx.x, w = tid >> 6, l = tid & 63;
    int mo = (w & 1) * 32, no = (w >> 1) * 32;
    int quad = l >> 4, col = l & 15;
    int m0 = mtile * 64 + mo;
    int n0 = ntile * 64 + no;
    for (int i = 0; i < 2; i++)
        for (int j = 0; j < 2; j++)
            for (int r = 0; r < 4; r++) {
                float val = acc[i][j][r];
                float p = __shfl_xor(val, 1);   // RoPE partner (adjacent col)
                int m = m0 + i * 16 + quad * 4 + r;
                int n = n0 + j * 16 + col;
                int d = n & 63;
                if (ntile < 16) {               // q (mem rows only, m in [64,128))
                    int jj = d >> 1;
                    float c = g_rc[m * 32 + jj], sn = g_rs[m * 32 + jj];
                    float o = (d & 1) ? (p * sn + val * c) : (val * c - p * sn);
                    g_qb[(((size_t)b * 16 + ntile) * 64 + (m - 64)) * 64 + d] = f2bf(o);
                } else if (ntile < 24) {        // k
                    int kvh = ntile - 16;
                    int jj = d >> 1;
                    float c = g_rc[m * 32 + jj], sn = g_rs[m * 32 + jj];
                    float o = (d & 1) ? (p * sn + val * c) : (val * c - p * sn);
                    g_kb[(((size_t)b * 8 + kvh) * 128 + m) * 64 + d] = f2bf(o);
                } else {                        // v (transposed store)
                    int kvh = ntile - 24;
                    g_vt[(((size_t)b * 8 + kvh) * 64 + d) * 128 + m] = f2bf(val);
                }
            }

    // ---- last-finisher ticket: winner runs attention for the ready head(s)
    int kvh = (ntile < 16) ? (ntile >> 1) : ((ntile < 24) ? (ntile - 16) : (ntile - 24));
    __threadfence();                            // release tile writes (device scope)
    __shared__ int s_wm;
    if (tid == 0) {
        int wm = 0;
        if (ntile < 16) {
            if (atomicAdd(&g_tk1[b * 16 + ntile], 1u) == 4u) wm = 1 << (ntile & 1);
        } else {
            if (atomicAdd(&g_tk1[b * 16 + 2 * kvh], 1u) == 4u)     wm |= 1;
            if (atomicAdd(&g_tk1[b * 16 + 2 * kvh + 1], 1u) == 4u) wm |= 2;
        }
        s_wm = wm;
    }
    __syncthreads();                            // also fences LDS reuse below
    int wm = s_wm;
    if (!wm) return;
    __threadfence();                            // acquire other blocks' tile writes
    unsigned short* att_s = (unsigned short*)smem;
    if (wm & 1) attn_one(b, 2 * kvh,     att_s);
    if (wm & 2) attn_one(b, 2 * kvh + 1, att_s);
    if (tid == 0) {
        if (wm & 1) atomicExch(&g_tk1[b * 16 + 2 * kvh],     0u);
        if (wm & 2) atomicExch(&g_tk1[b * 16 + 2 * kvh + 1], 0u);
    }
}

// ---------------- fused post-LN tail (winner block, 4 waves x 16 rows) ------
__device__ void ln_tail(int b, int s, float* __restrict__ dout,
                        const float* __restrict__ psc, const float* __restrict__ pbi,
                        const float* __restrict__ qsc, const float* __restrict__ qbi) {
    int tid = threadIdx.x, w = tid >> 6, l = tid & 63;
    float psA[16], pbA[16], qsA[16], qbA[16];
#pragma unroll
    for (int j = 0; j < 4; j++) {
        float4 t;
        t = ((const float4*)psc)[l * 4 + j]; psA[j*4]=t.x; psA[j*4+1]=t.y; psA[j*4+2]=t.z; psA[j*4+3]=t.w;
        t = ((const float4*)pbi)[l * 4 + j]; pbA[j*4]=t.x; pbA[j*4+1]=t.y; pbA[j*4+2]=t.z; pbA[j*4+3]=t.w;
        t = ((const float4*)qsc)[l * 4 + j]; qsA[j*4]=t.x; qsA[j*4+1]=t.y; qsA[j*4+2]=t.z; qsA[j*4+3]=t.w;
        t = ((const float4*)qbi)[l * 4 + j]; qbA[j*4]=t.x; qbA[j*4+1]=t.y; qbA[j*4+2]=t.z; qbA[j*4+3]=t.w;
    }
    for (int r = w; r < 64; r += 4) {
        size_t row = (size_t)b * 64 + r;
        const float4* op = (const float4*)(g_outp + row * 1024) + l * 4;
        float4*       mp = (float4*)(g_mem + row * 1024) + l * 4;
        float y[16];
        float sm = 0.f, ss = 0.f;
#pragma unroll
        for (int j = 0; j < 4; j++) {
            float4 o = op[j], m = mp[j];
            y[j*4+0] = o.x + m.x; y[j*4+1] = o.y + m.y;
            y[j*4+2] = o.z + m.z; y[j*4+3] = o.w + m.w;
        }
#pragma unroll
        for (int i = 0; i < 16; i++) { sm += y[i]; ss += y[i] * y[i]; }
        for (int off = 32; off > 0; off >>= 1) { sm += __shfl_xor(sm, off); ss += __shfl_xor(ss, off); }
        float mean = sm * (1.0f / 1024.0f);
        float rstd = rsqrtf(ss * (1.0f / 1024.0f) - mean * mean + 1e-6f);
        float nm[16];
#pragma unroll
        for (int i = 0; i < 16; i++) nm[i] = (y[i] - mean) * rstd * psA[i] + pbA[i];
        // store new mem (mask==1 on this path) + final output
#pragma unroll
        for (int j = 0; j < 4; j++) {
            float4 v4 = {nm[j*4+0], nm[j*4+1], nm[j*4+2], nm[j*4+3]};
            mp[j] = v4;
            if (s == NMs - 1) ((float4*)(dout + row * 1024))[l * 4 + j] = v4;
        }
        // h_mem = LN_pre(new_mem) for next step
        float s2 = 0.f, s2s = 0.f;
#pragma unroll
        for (int i = 0; i < 16; i++) { s2 += nm[i]; s2s += nm[i] * nm[i]; }
        for (int off = 32; off > 0; off >>= 1) { s2 += __shfl_xor(s2, off); s2s += __shfl_xor(s2s, off); }
        float mean2 = s2 * (1.0f / 1024.0f);
        float rstd2 = rsqrtf(s2s * (1.0f / 1024.0f) - mean2 * mean2 + 1e-6f);
        f16x8 h0, h1;
#pragma unroll
        for (int i = 0; i < 8; i++) h0[i] = (_Float16)((nm[i]     - mean2) * rstd2 * qsA[i]     + qbA[i]);
#pragma unroll
        for (int i = 0; i < 8; i++) h1[i] = (_Float16)((nm[8 + i] - mean2) * rstd2 * qsA[8 + i] + qbA[8 + i]);
        *(f16x8*)(g_hmem + row * 1024 + l * 16)     = h0;
        *(f16x8*)(g_hmem + row * 1024 + l * 16 + 8) = h1;
    }
}

// ---------------- step kernel 2: out = enc @ wo + fused LN tail -------------
// grid = 16*16 = 256, block 256. per-batch ticket (16 tiles), winner does LN.
__launch_bounds__(256)
__global__ void k_step2(int s, float* __restrict__ dout,
                        const float* __restrict__ psc, const float* __restrict__ pbi,
                        const float* __restrict__ qsc, const float* __restrict__ qbi) {
    int b = blockIdx.x >> 4, ntile = blockIdx.x & 15;
    int tid = threadIdx.x;
    if (!g_mask[b * 64 + s]) {
        if (s == NMs - 1) {                      // masked final step: mem -> out copy
            int r = ntile * 4 + (tid >> 6), l = tid & 63;
            const float4* src = (const float4*)(g_mem + ((size_t)b * 64 + r) * 1024);
            float4*       dst = (float4*)(dout + ((size_t)b * 64 + r) * 1024);
            for (int j = 0; j < 4; j++) dst[l * 4 + j] = src[l * 4 + j];
        }
        return;
    }
    const _Float16* Abase = g_enc + (size_t)b * 64 * 1024;
    const _Float16* Bbase = g_Wot + (size_t)ntile * 64 * 1024;
    __shared__ __align__(16) _Float16 As[64 * 40];
    __shared__ __align__(16) _Float16 Bs[64 * 40];
    f32x4 acc[2][2] = {};
    gemm_core(Abase, Bbase, As, Bs, acc);

    int w = tid >> 6, l = tid & 63;
    int mo = (w & 1) * 32, no = (w >> 1) * 32;
    int quad = l >> 4, col = l & 15;
    for (int i = 0; i < 2; i++)
        for (int j = 0; j < 2; j++)
            for (int r = 0; r < 4; r++) {
                int m = mo + i * 16 + quad * 4 + r;
                int n = ntile * 64 + no + j * 16 + col;
                g_outp[((size_t)b * 64 + m) * 1024 + n] = acc[i][j][r];
            }

    __threadfence();                             // release outp tile (device scope)
    __shared__ int s_win;
    if (tid == 0) s_win = (atomicAdd(&g_tk2[b], 1u) == 15u);
    __syncthreads();
    if (!s_win) return;
    __threadfence();                             // acquire other tiles of g_outp
    ln_tail(b, s, dout, psc, pbi, qsc, qbi);
    if (tid == 0) atomicExch(&g_tk2[b], 0u);
}

// ---------------------------------------------------------------------------
extern "C" void kernel_launch(void* const* d_in, const int* in_sizes, int n_in,
                              void* d_out, int out_size, void* d_ws, size_t ws_size,
                              hipStream_t stream) {
    (void)in_sizes; (void)n_in; (void)d_ws; (void)ws_size; (void)out_size;
    const float* hidden    = (const float*)d_in[0];
    const unsigned int* mk = (const unsigned int*)d_in[1];
    const float* mem_state = (const float*)d_in[2];
    const float* wq  = (const float*)d_in[3];
    const float* wk  = (const float*)d_in[4];
    const float* wv  = (const float*)d_in[5];
    const float* wo  = (const float*)d_in[6];
    const float* pre_s  = (const float*)d_in[7];
    const float* pre_b  = (const float*)d_in[8];
    const float* post_s = (const float*)d_in[9];
    const float* post_b = (const float*)d_in[10];
    float* out = (float*)d_out;

    k_transpose<<<dim3(16, 16), 256, 0, stream>>>(wq, 1024, 0);
    k_transpose<<<dim3(16, 8),  256, 0, stream>>>(wk, 512, 1);
    k_transpose<<<dim3(16, 8),  256, 0, stream>>>(wv, 512, 2);
    k_transpose<<<dim3(16, 16), 256, 0, stream>>>(wo, 1024, 3);
    k_rope<<<1, 128, 0, stream>>>();
    k_mask<<<1, 1024, 0, stream>>>(mk);
    k_ln_hx<<<NB * NMs * MBs, 256, 0, stream>>>(hidden, pre_s, pre_b);
    k_ln_init<<<NB * MEMm, 256, 0, stream>>>(mem_state, pre_s, pre_b);

    for (int s = 0; s < NMs; ++s) {
        k_step1<<<NB * 48, 256, 0, stream>>>(s);
        k_step2<<<NB * 16, 256, 0, stream>>>(s, out, post_s, post_b, pre_s, pre_b);
    }
}

// Round 2
// 4049.819 us; speedup vs baseline: 3.7728x; 3.7728x over previous
//
#include <hip/hip_runtime.h>

// ---------------------------------------------------------------------------
// RMT layer: B=16 chains x NM=64 sequential steps.
// R2: revert R1's fence-fusion (it destroyed L2 reuse: 46MB HBM/step).
//     Back to the proven 4-kernel/step structure + mask early-exit
//     (block-uniform) + single in-place mem buffer.
// ---------------------------------------------------------------------------

typedef __attribute__((ext_vector_type(8))) _Float16 f16x8;
typedef __attribute__((ext_vector_type(4))) _Float16 f16x4;
typedef __attribute__((ext_vector_type(8))) short    s16x8;
typedef __attribute__((ext_vector_type(4))) float    f32x4;

#define NB   16
#define NMs  64
#define MBs  64
#define Dm   1024
#define NHh  16
#define NKVh 8
#define HDd  64
#define MEMm 64
#define Sq   128

// ---------------- static device scratch -------------------------------------
__device__ __align__(16) _Float16      g_W1t[2048 * 1024];   // [n][k]: 0..1023 q, 1024..1535 k, 1536..2047 v
__device__ __align__(16) _Float16      g_Wot[1024 * 1024];   // wo^T [n][k]
__device__ __align__(16) float         g_rc[128 * 32];
__device__ __align__(16) float         g_rs[128 * 32];
__device__                unsigned char g_mask[NB * NMs];
__device__ __align__(16) _Float16      g_hx[(size_t)NB * NMs * MBs * Dm]; // LN'd x rows, f16 (134 MB)
__device__ __align__(16) _Float16      g_hmem[NB * MEMm * Dm];            // LN'd mem rows, f16
__device__ __align__(16) float         g_mem[NB * MEMm * Dm];             // fp32 mem, in-place
__device__ __align__(16) unsigned short g_qb[NB * NHh * 64 * 64];     // [b][h][m][d]  bf16
__device__ __align__(16) unsigned short g_kb[NB * NKVh * 128 * 64];   // [b][kvh][pos][d] bf16
__device__ __align__(16) unsigned short g_vt[NB * NKVh * 64 * 128];   // [b][kvh][d][pos] bf16 (transposed)
__device__ __align__(16) _Float16      g_enc[NB * 64 * Dm];           // attention out, f16
__device__ __align__(16) float         g_outp[NB * 64 * Dm];          // enc @ wo, fp32

// ---------------- helpers ---------------------------------------------------
__device__ __forceinline__ unsigned short f2bf(float x) {
    union { float f; unsigned u; } v; v.f = x;
    unsigned u = v.u;
    return (unsigned short)((u + 0x7fffu + ((u >> 16) & 1u)) >> 16);  // RNE
}
__device__ __forceinline__ float bf2f(unsigned short h) {
    union { unsigned u; float f; } v; v.u = ((unsigned)h) << 16; return v.f;
}

// block-wide (256 thr) mean/rstd from per-thread partial sums
__device__ __forceinline__ void block_stats(float s, float ss, float eps,
                                            float* mean, float* rstd) {
    for (int off = 32; off > 0; off >>= 1) {
        s  += __shfl_down(s, off);
        ss += __shfl_down(ss, off);
    }
    __shared__ float red[8];
    int wid = threadIdx.x >> 6, lane = threadIdx.x & 63;
    __syncthreads();                       // protect any previous use
    if (lane == 0) { red[wid] = s; red[4 + wid] = ss; }
    __syncthreads();
    float ts  = red[0] + red[1] + red[2] + red[3];
    float tss = red[4] + red[5] + red[6] + red[7];
    float m   = ts * (1.0f / 1024.0f);
    float var = tss * (1.0f / 1024.0f) - m * m;
    *mean = m;
    *rstd = rsqrtf(var + eps);
}

// ---------------- init kernels ----------------------------------------------
__global__ void k_transpose(const float* __restrict__ in, int ncols, int dsel) {
    _Float16* out = (dsel == 0) ? g_W1t
                  : (dsel == 1) ? (g_W1t + 1024 * 1024)
                  : (dsel == 2) ? (g_W1t + 1536 * 1024)
                                : g_Wot;
    __shared__ float tile[64][65];
    int bk = blockIdx.x, bn = blockIdx.y;
    int c = threadIdx.x & 63, rg = threadIdx.x >> 6;
    int k0 = bk * 64, n0 = bn * 64;
    for (int i = 0; i < 16; i++) {
        int r = rg * 16 + i;
        tile[r][c] = in[(size_t)(k0 + r) * ncols + n0 + c];
    }
    __syncthreads();
    for (int i = 0; i < 16; i++) {
        int r = rg * 16 + i;
        out[(size_t)(n0 + r) * 1024 + k0 + c] = (_Float16)tile[c][r];
    }
}

__global__ void k_rope() {
    int t = threadIdx.x;  // 128 positions
    for (int j = 0; j < 32; j++) {
        double f = pow(10000.0, -(double)j / 32.0);
        double a = (double)t * f;
        g_rc[t * 32 + j] = (float)cos(a);
        g_rs[t * 32 + j] = (float)sin(a);
    }
}

// normalize bool mask regardless of upload encoding (int32 / float32 / byte)
__global__ void k_mask(const unsigned int* __restrict__ ip) {
    __shared__ int byteFmt;
    int t = threadIdx.x;  // 1024
    if (t == 0) byteFmt = 0;
    __syncthreads();
    if (t < 256) {
        unsigned v = ip[t];
        if (!(v == 0u || v == 1u || v == 0x3F800000u)) byteFmt = 1;
    }
    __syncthreads();
    unsigned char m = byteFmt ? (((const unsigned char*)ip)[t] != 0)
                              : (ip[t] != 0u);
    g_mask[t] = m;
}

// LN of every x row (mem-independent) -> g_hx f16.  grid = 65536
__global__ void k_ln_hx(const float* __restrict__ x,
                        const float* __restrict__ sc, const float* __restrict__ bi) {
    size_t row = blockIdx.x;
    int t = threadIdx.x;
    float4 v = ((const float4*)(x + row * 1024))[t];
    float mean, rstd;
    block_stats(v.x + v.y + v.z + v.w,
                v.x * v.x + v.y * v.y + v.z * v.z + v.w * v.w, 1e-6f, &mean, &rstd);
    float4 s4 = ((const float4*)sc)[t];
    float4 b4 = ((const float4*)bi)[t];
    f16x4 o;
    o[0] = (_Float16)((v.x - mean) * rstd * s4.x + b4.x);
    o[1] = (_Float16)((v.y - mean) * rstd * s4.y + b4.y);
    o[2] = (_Float16)((v.z - mean) * rstd * s4.z + b4.z);
    o[3] = (_Float16)((v.w - mean) * rstd * s4.w + b4.w);
    *(f16x4*)(g_hx + row * 1024 + t * 4) = o;
}

// broadcast mem_state to per-batch mem + h_mem = LN_pre(mem_state). grid = 1024
__global__ void k_ln_init(const float* __restrict__ ms,
                          const float* __restrict__ sc, const float* __restrict__ bi) {
    int b = blockIdx.x >> 6, r = blockIdx.x & 63;
    int t = threadIdx.x;
    float4 v = ((const float4*)(ms + (size_t)r * 1024))[t];
    ((float4*)(g_mem + ((size_t)b * 64 + r) * 1024))[t] = v;
    float mean, rstd;
    block_stats(v.x + v.y + v.z + v.w,
                v.x * v.x + v.y * v.y + v.z * v.z + v.w * v.w, 1e-6f, &mean, &rstd);
    float4 s4 = ((const float4*)sc)[t];
    float4 b4 = ((const float4*)bi)[t];
    f16x4 o;
    o[0] = (_Float16)((v.x - mean) * rstd * s4.x + b4.x);
    o[1] = (_Float16)((v.y - mean) * rstd * s4.y + b4.y);
    o[2] = (_Float16)((v.z - mean) * rstd * s4.z + b4.z);
    o[3] = (_Float16)((v.w - mean) * rstd * s4.w + b4.w);
    *(f16x4*)(g_hmem + ((size_t)b * 64 + r) * 1024 + t * 4) = o;
}

// ---------------- 64x64-tile f16 MFMA GEMM core (K=1024) --------------------
__device__ __forceinline__ void gemm_core(const _Float16* __restrict__ Abase,
                                          const _Float16* __restrict__ Bbase,
                                          _Float16* As, _Float16* Bs,
                                          f32x4 acc[2][2]) {
    int tid = threadIdx.x;
    int w = tid >> 6, l = tid & 63;
    int mo = (w & 1) * 32, no = (w >> 1) * 32;
    int sr = tid >> 2, sk = (tid & 3) * 8;
    int fr = l & 15, fq = (l >> 4) * 8;
    for (int kt = 0; kt < 32; ++kt) {
        f16x8 av = *(const f16x8*)(Abase + (size_t)sr * 1024 + kt * 32 + sk);
        f16x8 bv = *(const f16x8*)(Bbase + (size_t)sr * 1024 + kt * 32 + sk);
        __syncthreads();
        *(f16x8*)&As[sr * 40 + sk] = av;
        *(f16x8*)&Bs[sr * 40 + sk] = bv;
        __syncthreads();
        f16x8 a0 = *(const f16x8*)&As[(mo + fr) * 40 + fq];
        f16x8 a1 = *(const f16x8*)&As[(mo + 16 + fr) * 40 + fq];
        f16x8 b0 = *(const f16x8*)&Bs[(no + fr) * 40 + fq];
        f16x8 b1 = *(const f16x8*)&Bs[(no + 16 + fr) * 40 + fq];
        acc[0][0] = __builtin_amdgcn_mfma_f32_16x16x32_f16(a0, b0, acc[0][0], 0, 0, 0);
        acc[0][1] = __builtin_amdgcn_mfma_f32_16x16x32_f16(a0, b1, acc[0][1], 0, 0, 0);
        acc[1][0] = __builtin_amdgcn_mfma_f32_16x16x32_f16(a1, b0, acc[1][0], 0, 0, 0);
        acc[1][1] = __builtin_amdgcn_mfma_f32_16x16x32_f16(a1, b1, acc[1][1], 0, 0, 0);
    }
}

// QKV GEMM + RoPE + bf16 round + scatter.  grid = 16*48 = 768, block 256.
// tiles: mtile0 (x rows): ntile 16..31 (k,v only); mtile1 (mem rows): ntile 0..31
__launch_bounds__(256)
__global__ void k_gemm1(int s) {
    int bid = blockIdx.x;
    int b = bid / 48, t48 = bid % 48;
    if (!g_mask[b * 64 + s]) return;        // masked step: batch unchanged, skip
    int mtile = (t48 < 16) ? 0 : 1;
    int ntile = (t48 < 16) ? (16 + t48) : (t48 - 16);
    const _Float16* Abase = (mtile == 0)
        ? (g_hx + ((size_t)(b * NMs + s) * 64) * 1024)
        : (g_hmem + (size_t)b * 64 * 1024);
    const _Float16* Bbase = g_W1t + (size_t)ntile * 64 * 1024;
    __shared__ __align__(16) _Float16 As[64 * 40];
    __shared__ __align__(16) _Float16 Bs[64 * 40];
    f32x4 acc[2][2] = {};
    gemm_core(Abase, Bbase, As, Bs, acc);

    int tid = threadIdx.x, w = tid >> 6, l = tid & 63;
    int mo = (w & 1) * 32, no = (w >> 1) * 32;
    int quad = l >> 4, col = l & 15;
    int m0 = mtile * 64 + mo;
    int n0 = ntile * 64 + no;
    for (int i = 0; i < 2; i++)
        for (int j = 0; j < 2; j++)
            for (int r = 0; r < 4; r++) {
                float val = acc[i][j][r];
                float p = __shfl_xor(val, 1);   // RoPE partner (adjacent col)
                int m = m0 + i * 16 + quad * 4 + r;
                int n = n0 + j * 16 + col;
                int d = n & 63;
                if (ntile < 16) {               // q (mem rows only, m in [64,128))
                    int jj = d >> 1;
                    float c = g_rc[m * 32 + jj], sn = g_rs[m * 32 + jj];
                    float o = (d & 1) ? (p * sn + val * c) : (val * c - p * sn);
                    g_qb[(((size_t)b * 16 + ntile) * 64 + (m - 64)) * 64 + d] = f2bf(o);
                } else if (ntile < 24) {        // k
                    int kvh = ntile - 16;
                    int jj = d >> 1;
                    float c = g_rc[m * 32 + jj], sn = g_rs[m * 32 + jj];
                    float o = (d & 1) ? (p * sn + val * c) : (val * c - p * sn);
                    g_kb[(((size_t)b * 8 + kvh) * 128 + m) * 64 + d] = f2bf(o);
                } else {                        // v (transposed store)
                    int kvh = ntile - 24;
                    g_vt[(((size_t)b * 8 + kvh) * 64 + d) * 128 + m] = f2bf(val);
                }
            }
}

// attention per (b,h): [64q x 128k], bf16 MFMA, fp32 softmax. grid=256, block 256
__launch_bounds__(256)
__global__ void k_attn(int s) {
    int b = blockIdx.x >> 4, h = blockIdx.x & 15, kvh = h >> 1;
    if (!g_mask[b * 64 + s]) return;
    int tid = threadIdx.x, w = tid >> 6, l = tid & 63;
    int fr = l & 15, fq = (l >> 4) * 8;
    const unsigned short* qp = g_qb + ((size_t)b * 16 + h) * 64 * 64;
    const unsigned short* kp = g_kb + ((size_t)b * 8 + kvh) * 128 * 64;
    const unsigned short* vp = g_vt + ((size_t)b * 8 + kvh) * 64 * 128;

    s16x8 aq0 = *(const s16x8*)(qp + (w * 16 + fr) * 64 + fq);
    s16x8 aq1 = *(const s16x8*)(qp + (w * 16 + fr) * 64 + 32 + fq);
    f32x4 sc[8];
    for (int nt = 0; nt < 8; nt++) {
        sc[nt] = (f32x4){0.f, 0.f, 0.f, 0.f};
        s16x8 kb0 = *(const s16x8*)(kp + (nt * 16 + fr) * 64 + fq);
        s16x8 kb1 = *(const s16x8*)(kp + (nt * 16 + fr) * 64 + 32 + fq);
        sc[nt] = __builtin_amdgcn_mfma_f32_16x16x32_bf16(aq0, kb0, sc[nt], 0, 0, 0);
        sc[nt] = __builtin_amdgcn_mfma_f32_16x16x32_bf16(aq1, kb1, sc[nt], 0, 0, 0);
    }
    // match reference: bf16-round logits, *scale, fp32 softmax, bf16-round att
    float lv[8][4];
    for (int nt = 0; nt < 8; nt++)
        for (int r = 0; r < 4; r++)
            lv[nt][r] = bf2f(f2bf(sc[nt][r])) * 0.125f;

    int quad = l >> 4;
    __shared__ __align__(16) unsigned short att_s[64 * 136];
    for (int r = 0; r < 4; r++) {
        float mx = -1e30f;
        for (int nt = 0; nt < 8; nt++) mx = fmaxf(mx, lv[nt][r]);
        for (int off = 1; off < 16; off <<= 1) mx = fmaxf(mx, __shfl_xor(mx, off));
        float sm = 0.f;
        for (int nt = 0; nt < 8; nt++) { lv[nt][r] = expf(lv[nt][r] - mx); sm += lv[nt][r]; }
        for (int off = 1; off < 16; off <<= 1) sm += __shfl_xor(sm, off);
        float inv = 1.0f / sm;
        int row = w * 16 + quad * 4 + r;
        for (int nt = 0; nt < 8; nt++)
            att_s[row * 136 + nt * 16 + fr] = f2bf(lv[nt][r] * inv);
    }
    // PV: att [64x128] @ v^T-layout [d][pos]; strips are wave-local (no barrier)
    f32x4 o[4];
    for (int nt = 0; nt < 4; nt++) o[nt] = (f32x4){0.f, 0.f, 0.f, 0.f};
    for (int kt = 0; kt < 4; kt++) {
        s16x8 a = *(const s16x8*)&att_s[(w * 16 + fr) * 136 + kt * 32 + fq];
        for (int nt = 0; nt < 4; nt++) {
            s16x8 bv = *(const s16x8*)(vp + (nt * 16 + fr) * 128 + kt * 32 + fq);
            o[nt] = __builtin_amdgcn_mfma_f32_16x16x32_bf16(a, bv, o[nt], 0, 0, 0);
        }
    }
    for (int nt = 0; nt < 4; nt++)
        for (int r = 0; r < 4; r++) {
            int m = w * 16 + quad * 4 + r;
            int d = nt * 16 + fr;
            g_enc[((size_t)b * 64 + m) * 1024 + h * 64 + d] =
                (_Float16)bf2f(f2bf(o[nt][r]));   // match ref bf16 enc, exact ->f16
        }
}

// out = enc @ wo.  grid = 16*16 = 256, block 256
__launch_bounds__(256)
__global__ void k_gemm2(int s) {
    int b = blockIdx.x >> 4, ntile = blockIdx.x & 15;
    if (!g_mask[b * 64 + s]) return;
    const _Float16* Abase = g_enc + (size_t)b * 64 * 1024;
    const _Float16* Bbase = g_Wot + (size_t)ntile * 64 * 1024;
    __shared__ __align__(16) _Float16 As[64 * 40];
    __shared__ __align__(16) _Float16 Bs[64 * 40];
    f32x4 acc[2][2] = {};
    gemm_core(Abase, Bbase, As, Bs, acc);

    int tid = threadIdx.x, w = tid >> 6, l = tid & 63;
    int mo = (w & 1) * 32, no = (w >> 1) * 32;
    int quad = l >> 4, col = l & 15;
    for (int i = 0; i < 2; i++)
        for (int j = 0; j < 2; j++)
            for (int r = 0; r < 4; r++) {
                int m = mo + i * 16 + quad * 4 + r;
                int n = ntile * 64 + no + j * 16 + col;
                g_outp[((size_t)b * 64 + m) * 1024 + n] = acc[i][j][r];
            }
}

// new_mem = LN_post(out+mem) in place; also h_mem = LN_pre(new_mem). grid=1024
__global__ void k_ln2(int s, float* __restrict__ dout,
                      const float* __restrict__ psc, const float* __restrict__ pbi,
                      const float* __restrict__ qsc, const float* __restrict__ qbi) {
    int b = blockIdx.x >> 6, r = blockIdx.x & 63;
    int t = threadIdx.x;
    size_t row = (size_t)b * 64 + r;
    if (!g_mask[b * 64 + s]) {
        if (s == NMs - 1)   // masked final step: mem -> out copy
            ((float4*)(dout + row * 1024))[t] = ((const float4*)(g_mem + row * 1024))[t];
        return;
    }
    float4 ov = ((const float4*)(g_outp + row * 1024))[t];
    float4 mv = ((const float4*)(g_mem + row * 1024))[t];
    float4 y = {ov.x + mv.x, ov.y + mv.y, ov.z + mv.z, ov.w + mv.w};
    float mean, rstd;
    block_stats(y.x + y.y + y.z + y.w,
                y.x * y.x + y.y * y.y + y.z * y.z + y.w * y.w, 1e-6f, &mean, &rstd);
    float4 s4 = ((const float4*)psc)[t];
    float4 b4 = ((const float4*)pbi)[t];
    float4 nm = {(y.x - mean) * rstd * s4.x + b4.x,
                 (y.y - mean) * rstd * s4.y + b4.y,
                 (y.z - mean) * rstd * s4.z + b4.z,
                 (y.w - mean) * rstd * s4.w + b4.w};
    ((float4*)(g_mem + row * 1024))[t] = nm;        // in-place (row-private)
    if (s == NMs - 1)
        ((float4*)(dout + row * 1024))[t] = nm;
    // h for next step's mem rows
    float m2, rs2;
    block_stats(nm.x + nm.y + nm.z + nm.w,
                nm.x * nm.x + nm.y * nm.y + nm.z * nm.z + nm.w * nm.w,
                1e-6f, &m2, &rs2);
    float4 c4 = ((const float4*)qsc)[t];
    float4 d4 = ((const float4*)qbi)[t];
    f16x4 o;
    o[0] = (_Float16)((nm.x - m2) * rs2 * c4.x + d4.x);
    o[1] = (_Float16)((nm.y - m2) * rs2 * c4.y + d4.y);
    o[2] = (_Float16)((nm.z - m2) * rs2 * c4.z + d4.z);
    o[3] = (_Float16)((nm.w - m2) * rs2 * c4.w + d4.w);
    *(f16x4*)(g_hmem + row * 1024 + t * 4) = o;
}

// ---------------------------------------------------------------------------
extern "C" void kernel_launch(void* const* d_in, const int* in_sizes, int n_in,
                              void* d_out, int out_size, void* d_ws, size_t ws_size,
                              hipStream_t stream) {
    (void)in_sizes; (void)n_in; (void)d_ws; (void)ws_size; (void)out_size;
    const float* hidden    = (const float*)d_in[0];
    const unsigned int* mk = (const unsigned int*)d_in[1];
    const float* mem_state = (const float*)d_in[2];
    const float* wq  = (const float*)d_in[3];
    const float* wk  = (const float*)d_in[4];
    const float* wv  = (const float*)d_in[5];
    const float* wo  = (const float*)d_in[6];
    const float* pre_s  = (const float*)d_in[7];
    const float* pre_b  = (const float*)d_in[8];
    const float* post_s = (const float*)d_in[9];
    const float* post_b = (const float*)d_in[10];
    float* out = (float*)d_out;

    k_transpose<<<dim3(16, 16), 256, 0, stream>>>(wq, 1024, 0);
    k_transpose<<<dim3(16, 8),  256, 0, stream>>>(wk, 512, 1);
    k_transpose<<<dim3(16, 8),  256, 0, stream>>>(wv, 512, 2);
    k_transpose<<<dim3(16, 16), 256, 0, stream>>>(wo, 1024, 3);
    k_rope<<<1, 128, 0, stream>>>();
    k_mask<<<1, 1024, 0, stream>>>(mk);
    k_ln_hx<<<NB * NMs * MBs, 256, 0, stream>>>(hidden, pre_s, pre_b);
    k_ln_init<<<NB * MEMm, 256, 0, stream>>>(mem_state, pre_s, pre_b);

    for (int s = 0; s < NMs; ++s) {
        k_gemm1<<<NB * 48, 256, 0, stream>>>(s);
        k_attn<<<NB * NHh, 256, 0, stream>>>(s);
        k_gemm2<<<NB * 16, 256, 0, stream>>>(s);
        k_ln2<<<NB * MEMm, 256, 0, stream>>>(s, out, post_s, post_b, pre_s, pre_b);
    }
}

// Round 4
// 3978.680 us; speedup vs baseline: 3.8403x; 1.0179x over previous
//
#include <hip/hip_runtime.h>

// ---------------------------------------------------------------------------
// RMT layer: B=16 chains x NM=64 sequential steps.
// R4: R3 hoist architecture (x-row K/V computed once upfront for all steps),
//     but k_kv_big rebuilt on the PROVEN reg-staged LDS pattern (no
//     global_load_lds / inline asm) after R3's container failure.
// ---------------------------------------------------------------------------

typedef __attribute__((ext_vector_type(8))) _Float16 f16x8;
typedef __attribute__((ext_vector_type(4))) _Float16 f16x4;
typedef __attribute__((ext_vector_type(8))) short    s16x8;
typedef __attribute__((ext_vector_type(4))) float    f32x4;

#define NB   16
#define NMs  64
#define MBs  64
#define Dm   1024
#define NHh  16
#define NKVh 8
#define HDd  64
#define MEMm 64
#define Sq   128

// ---------------- static device scratch -------------------------------------
__device__ __align__(16) _Float16      g_W1t[2048 * 1024];   // [n][k]: 0..1023 q^T, 1024..1535 k^T, 1536..2047 v^T
__device__ __align__(16) _Float16      g_Wot[1024 * 1024];   // wo^T [n][k]
__device__ __align__(16) float         g_rc[128 * 32];
__device__ __align__(16) float         g_rs[128 * 32];
__device__                unsigned char g_mask[NB * NMs];
__device__ __align__(16) _Float16      g_hx[(size_t)NB * NMs * MBs * Dm]; // LN'd x rows, f16 (134 MB)
__device__ __align__(16) _Float16      g_hmem[NB * MEMm * Dm];            // LN'd mem rows, f16
__device__ __align__(16) float         g_mem[NB * MEMm * Dm];             // fp32 mem, in-place
// hoisted x-row K/V for ALL (b,s):  g = b*64+s
__device__ __align__(16) unsigned short g_kbs[(size_t)1024 * 8 * 64 * 64]; // [g][kvh][pos][d]  bf16 (67 MB)
__device__ __align__(16) unsigned short g_vts[(size_t)1024 * 8 * 64 * 64]; // [g][kvh][d][pos]  bf16 (67 MB)
// per-step mem-row Q/K/V
__device__ __align__(16) unsigned short g_qb[NB * NHh * 64 * 64];     // [b][h][m][d]  bf16
__device__ __align__(16) unsigned short g_kbm[NB * NKVh * 64 * 64];   // [b][kvh][pos-64][d] bf16
__device__ __align__(16) unsigned short g_vtm[NB * NKVh * 64 * 64];   // [b][kvh][d][pos-64] bf16
__device__ __align__(16) _Float16      g_enc[NB * 64 * Dm];           // attention out, f16
__device__ __align__(16) float         g_outp[NB * 64 * Dm];          // enc @ wo, fp32

// ---------------- helpers ---------------------------------------------------
__device__ __forceinline__ unsigned short f2bf(float x) {
    union { float f; unsigned u; } v; v.f = x;
    unsigned u = v.u;
    return (unsigned short)((u + 0x7fffu + ((u >> 16) & 1u)) >> 16);  // RNE
}
__device__ __forceinline__ float bf2f(unsigned short h) {
    union { unsigned u; float f; } v; v.u = ((unsigned)h) << 16; return v.f;
}

__device__ __forceinline__ void block_stats(float s, float ss, float eps,
                                            float* mean, float* rstd) {
    for (int off = 32; off > 0; off >>= 1) {
        s  += __shfl_down(s, off);
        ss += __shfl_down(ss, off);
    }
    __shared__ float red[8];
    int wid = threadIdx.x >> 6, lane = threadIdx.x & 63;
    __syncthreads();
    if (lane == 0) { red[wid] = s; red[4 + wid] = ss; }
    __syncthreads();
    float ts  = red[0] + red[1] + red[2] + red[3];
    float tss = red[4] + red[5] + red[6] + red[7];
    float m   = ts * (1.0f / 1024.0f);
    float var = tss * (1.0f / 1024.0f) - m * m;
    *mean = m;
    *rstd = rsqrtf(var + eps);
}

// ---------------- init kernels ----------------------------------------------
__global__ void k_transpose(const float* __restrict__ in, int ncols, int dsel) {
    _Float16* out = (dsel == 0) ? g_W1t
                  : (dsel == 1) ? (g_W1t + 1024 * 1024)
                  : (dsel == 2) ? (g_W1t + 1536 * 1024)
                                : g_Wot;
    __shared__ float tile[64][65];
    int bk = blockIdx.x, bn = blockIdx.y;
    int c = threadIdx.x & 63, rg = threadIdx.x >> 6;
    int k0 = bk * 64, n0 = bn * 64;
    for (int i = 0; i < 16; i++) {
        int r = rg * 16 + i;
        tile[r][c] = in[(size_t)(k0 + r) * ncols + n0 + c];
    }
    __syncthreads();
    for (int i = 0; i < 16; i++) {
        int r = rg * 16 + i;
        out[(size_t)(n0 + r) * 1024 + k0 + c] = (_Float16)tile[c][r];
    }
}

__global__ void k_rope() {
    int t = threadIdx.x;  // 128 positions
    for (int j = 0; j < 32; j++) {
        double f = pow(10000.0, -(double)j / 32.0);
        double a = (double)t * f;
        g_rc[t * 32 + j] = (float)cos(a);
        g_rs[t * 32 + j] = (float)sin(a);
    }
}

__global__ void k_mask(const unsigned int* __restrict__ ip) {
    __shared__ int byteFmt;
    int t = threadIdx.x;  // 1024
    if (t == 0) byteFmt = 0;
    __syncthreads();
    if (t < 256) {
        unsigned v = ip[t];
        if (!(v == 0u || v == 1u || v == 0x3F800000u)) byteFmt = 1;
    }
    __syncthreads();
    unsigned char m = byteFmt ? (((const unsigned char*)ip)[t] != 0)
                              : (ip[t] != 0u);
    g_mask[t] = m;
}

__global__ void k_ln_hx(const float* __restrict__ x,
                        const float* __restrict__ sc, const float* __restrict__ bi) {
    size_t row = blockIdx.x;
    int t = threadIdx.x;
    float4 v = ((const float4*)(x + row * 1024))[t];
    float mean, rstd;
    block_stats(v.x + v.y + v.z + v.w,
                v.x * v.x + v.y * v.y + v.z * v.z + v.w * v.w, 1e-6f, &mean, &rstd);
    float4 s4 = ((const float4*)sc)[t];
    float4 b4 = ((const float4*)bi)[t];
    f16x4 o;
    o[0] = (_Float16)((v.x - mean) * rstd * s4.x + b4.x);
    o[1] = (_Float16)((v.y - mean) * rstd * s4.y + b4.y);
    o[2] = (_Float16)((v.z - mean) * rstd * s4.z + b4.z);
    o[3] = (_Float16)((v.w - mean) * rstd * s4.w + b4.w);
    *(f16x4*)(g_hx + row * 1024 + t * 4) = o;
}

__global__ void k_ln_init(const float* __restrict__ ms,
                          const float* __restrict__ sc, const float* __restrict__ bi) {
    int b = blockIdx.x >> 6, r = blockIdx.x & 63;
    int t = threadIdx.x;
    float4 v = ((const float4*)(ms + (size_t)r * 1024))[t];
    ((float4*)(g_mem + ((size_t)b * 64 + r) * 1024))[t] = v;
    float mean, rstd;
    block_stats(v.x + v.y + v.z + v.w,
                v.x * v.x + v.y * v.y + v.z * v.z + v.w * v.w, 1e-6f, &mean, &rstd);
    float4 s4 = ((const float4*)sc)[t];
    float4 b4 = ((const float4*)bi)[t];
    f16x4 o;
    o[0] = (_Float16)((v.x - mean) * rstd * s4.x + b4.x);
    o[1] = (_Float16)((v.y - mean) * rstd * s4.y + b4.y);
    o[2] = (_Float16)((v.z - mean) * rstd * s4.z + b4.z);
    o[3] = (_Float16)((v.w - mean) * rstd * s4.w + b4.w);
    *(f16x4*)(g_hmem + ((size_t)b * 64 + r) * 1024 + t * 4) = o;
}

// ---------------- upfront x-row K/V GEMM (128^2 tile, reg-staged LDS) -------
// C[65536 x 1024] = g_hx @ [wk | wv];  epilogue: RoPE(K) + bf16 + scatter.
// grid = 512 mt x 8 nt = 4096 blocks, 256 threads (2x2 waves, 64x64 each).
__launch_bounds__(256)
__global__ void k_kv_big() {
    int bid = blockIdx.x;
    int mt = bid >> 3, ntb = bid & 7;
    size_t m0 = (size_t)mt * 128;
    int n0 = ntb * 128;
    const _Float16* Ab = g_hx;                         // [65536][1024]
    const _Float16* Bb = g_W1t + (size_t)1024 * 1024;  // [1024][1024]: 0..511 k^T, 512..1023 v^T
    __shared__ __align__(16) _Float16 As[128 * 40];
    __shared__ __align__(16) _Float16 Bs[128 * 40];
    int tid = threadIdx.x;
    int w = tid >> 6, l = tid & 63;
    int wr = w >> 1, wc = w & 1;
    int fr = l & 15, fq = (l >> 4) * 8;
    int sr = tid >> 2, sk = (tid & 3) * 8;             // staging map: 2 rows per thread
    f32x4 acc[4][4] = {};
    for (int kt = 0; kt < 32; ++kt) {
        f16x8 a0 = *(const f16x8*)(Ab + (m0 + sr) * 1024 + kt * 32 + sk);
        f16x8 a1 = *(const f16x8*)(Ab + (m0 + 64 + sr) * 1024 + kt * 32 + sk);
        f16x8 b0 = *(const f16x8*)(Bb + (size_t)(n0 + sr) * 1024 + kt * 32 + sk);
        f16x8 b1 = *(const f16x8*)(Bb + (size_t)(n0 + 64 + sr) * 1024 + kt * 32 + sk);
        __syncthreads();
        *(f16x8*)&As[sr * 40 + sk] = a0;
        *(f16x8*)&As[(64 + sr) * 40 + sk] = a1;
        *(f16x8*)&Bs[sr * 40 + sk] = b0;
        *(f16x8*)&Bs[(64 + sr) * 40 + sk] = b1;
        __syncthreads();
        f16x8 af[4], bf[4];
#pragma unroll
        for (int mf = 0; mf < 4; mf++) af[mf] = *(const f16x8*)&As[(wr * 64 + mf * 16 + fr) * 40 + fq];
#pragma unroll
        for (int nf = 0; nf < 4; nf++) bf[nf] = *(const f16x8*)&Bs[(wc * 64 + nf * 16 + fr) * 40 + fq];
#pragma unroll
        for (int mf = 0; mf < 4; mf++)
#pragma unroll
            for (int nf = 0; nf < 4; nf++)
                acc[mf][nf] = __builtin_amdgcn_mfma_f32_16x16x32_f16(af[mf], bf[nf], acc[mf][nf], 0, 0, 0);
    }
    int quad = l >> 4, col = l & 15;
    if (ntb < 4) {                                     // K half: RoPE + scatter
        for (int mf = 0; mf < 4; mf++)
            for (int nf = 0; nf < 4; nf++)
                for (int r = 0; r < 4; r++) {
                    float val = acc[mf][nf][r];
                    float p = __shfl_xor(val, 1);      // adjacent-col RoPE partner
                    size_t mg = m0 + wr * 64 + mf * 16 + quad * 4 + r;
                    size_t g = mg >> 6;
                    int xr = (int)(mg & 63);           // position 0..63
                    int ng = n0 + wc * 64 + nf * 16 + col;
                    int kvh = ng >> 6, d = ng & 63, jj = d >> 1;
                    float c = g_rc[xr * 32 + jj], sn = g_rs[xr * 32 + jj];
                    float o = (d & 1) ? (p * sn + val * c) : (val * c - p * sn);
                    g_kbs[((g * 8 + kvh) * 64 + xr) * 64 + d] = f2bf(o);
                }
    } else {                                           // V half: transposed scatter
        for (int mf = 0; mf < 4; mf++)
            for (int nf = 0; nf < 4; nf++)
                for (int r = 0; r < 4; r++) {
                    float val = acc[mf][nf][r];
                    size_t mg = m0 + wr * 64 + mf * 16 + quad * 4 + r;
                    size_t g = mg >> 6;
                    int xr = (int)(mg & 63);
                    int nv = n0 + wc * 64 + nf * 16 + col - 512;
                    int kvh = nv >> 6, d = nv & 63;
                    g_vts[((g * 8 + kvh) * 64 + d) * 64 + xr] = f2bf(val);
                }
    }
}

// ---------------- 64x64-tile f16 MFMA GEMM core (K=1024) --------------------
__device__ __forceinline__ void gemm_core(const _Float16* __restrict__ Abase,
                                          const _Float16* __restrict__ Bbase,
                                          _Float16* As, _Float16* Bs,
                                          f32x4 acc[2][2]) {
    int tid = threadIdx.x;
    int w = tid >> 6, l = tid & 63;
    int mo = (w & 1) * 32, no = (w >> 1) * 32;
    int sr = tid >> 2, sk = (tid & 3) * 8;
    int fr = l & 15, fq = (l >> 4) * 8;
    for (int kt = 0; kt < 32; ++kt) {
        f16x8 av = *(const f16x8*)(Abase + (size_t)sr * 1024 + kt * 32 + sk);
        f16x8 bv = *(const f16x8*)(Bbase + (size_t)sr * 1024 + kt * 32 + sk);
        __syncthreads();
        *(f16x8*)&As[sr * 40 + sk] = av;
        *(f16x8*)&Bs[sr * 40 + sk] = bv;
        __syncthreads();
        f16x8 a0 = *(const f16x8*)&As[(mo + fr) * 40 + fq];
        f16x8 a1 = *(const f16x8*)&As[(mo + 16 + fr) * 40 + fq];
        f16x8 b0 = *(const f16x8*)&Bs[(no + fr) * 40 + fq];
        f16x8 b1 = *(const f16x8*)&Bs[(no + 16 + fr) * 40 + fq];
        acc[0][0] = __builtin_amdgcn_mfma_f32_16x16x32_f16(a0, b0, acc[0][0], 0, 0, 0);
        acc[0][1] = __builtin_amdgcn_mfma_f32_16x16x32_f16(a0, b1, acc[0][1], 0, 0, 0);
        acc[1][0] = __builtin_amdgcn_mfma_f32_16x16x32_f16(a1, b0, acc[1][0], 0, 0, 0);
        acc[1][1] = __builtin_amdgcn_mfma_f32_16x16x32_f16(a1, b1, acc[1][1], 0, 0, 0);
    }
}

// per-step mem-row Q/K/V GEMM + RoPE + bf16 + scatter. grid = 16*32, block 256
__launch_bounds__(256)
__global__ void k_gemm1(int s) {
    int bid = blockIdx.x;
    int b = bid >> 5, ntile = bid & 31;
    if (!g_mask[b * 64 + s]) return;
    const _Float16* Abase = g_hmem + (size_t)b * 64 * 1024;
    const _Float16* Bbase = g_W1t + (size_t)ntile * 64 * 1024;
    __shared__ __align__(16) _Float16 As[64 * 40];
    __shared__ __align__(16) _Float16 Bs[64 * 40];
    f32x4 acc[2][2] = {};
    gemm_core(Abase, Bbase, As, Bs, acc);

    int tid = threadIdx.x, w = tid >> 6, l = tid & 63;
    int mo = (w & 1) * 32, no = (w >> 1) * 32;
    int quad = l >> 4, col = l & 15;
    int m0 = 64 + mo;                       // mem rows: positions 64..127
    int n0 = ntile * 64 + no;
    for (int i = 0; i < 2; i++)
        for (int j = 0; j < 2; j++)
            for (int r = 0; r < 4; r++) {
                float val = acc[i][j][r];
                float p = __shfl_xor(val, 1);
                int m = m0 + i * 16 + quad * 4 + r;
                int n = n0 + j * 16 + col;
                int d = n & 63;
                if (ntile < 16) {               // q
                    int jj = d >> 1;
                    float c = g_rc[m * 32 + jj], sn = g_rs[m * 32 + jj];
                    float o = (d & 1) ? (p * sn + val * c) : (val * c - p * sn);
                    g_qb[(((size_t)b * 16 + ntile) * 64 + (m - 64)) * 64 + d] = f2bf(o);
                } else if (ntile < 24) {        // k (positions 64..127)
                    int kvh = ntile - 16;
                    int jj = d >> 1;
                    float c = g_rc[m * 32 + jj], sn = g_rs[m * 32 + jj];
                    float o = (d & 1) ? (p * sn + val * c) : (val * c - p * sn);
                    g_kbm[(((size_t)b * 8 + kvh) * 64 + (m - 64)) * 64 + d] = f2bf(o);
                } else {                        // v transposed
                    int kvh = ntile - 24;
                    g_vtm[(((size_t)b * 8 + kvh) * 64 + d) * 64 + (m - 64)] = f2bf(val);
                }
            }
}

// attention per (b,h): [64q x 128k]; K/V pos 0..63 from hoisted bufs. grid=256
__launch_bounds__(256)
__global__ void k_attn(int s) {
    int b = blockIdx.x >> 4, h = blockIdx.x & 15, kvh = h >> 1;
    if (!g_mask[b * 64 + s]) return;
    int tid = threadIdx.x, w = tid >> 6, l = tid & 63;
    int fr = l & 15, fq = (l >> 4) * 8;
    const unsigned short* qp  = g_qb  + ((size_t)b * 16 + h) * 64 * 64;
    const unsigned short* kps = g_kbs + ((size_t)(b * 64 + s) * 8 + kvh) * 4096; // pos 0..63
    const unsigned short* kpm = g_kbm + ((size_t)b * 8 + kvh) * 4096;            // pos 64..127
    const unsigned short* vps = g_vts + ((size_t)(b * 64 + s) * 8 + kvh) * 4096; // [d][pos0..63]
    const unsigned short* vpm = g_vtm + ((size_t)b * 8 + kvh) * 4096;            // [d][pos64..127]

    s16x8 aq0 = *(const s16x8*)(qp + (w * 16 + fr) * 64 + fq);
    s16x8 aq1 = *(const s16x8*)(qp + (w * 16 + fr) * 64 + 32 + fq);
    f32x4 sc[8];
    for (int nt = 0; nt < 8; nt++) {
        sc[nt] = (f32x4){0.f, 0.f, 0.f, 0.f};
        const unsigned short* kr = (nt < 4) ? (kps + (nt * 16 + fr) * 64)
                                            : (kpm + ((nt - 4) * 16 + fr) * 64);
        s16x8 kb0 = *(const s16x8*)(kr + fq);
        s16x8 kb1 = *(const s16x8*)(kr + 32 + fq);
        sc[nt] = __builtin_amdgcn_mfma_f32_16x16x32_bf16(aq0, kb0, sc[nt], 0, 0, 0);
        sc[nt] = __builtin_amdgcn_mfma_f32_16x16x32_bf16(aq1, kb1, sc[nt], 0, 0, 0);
    }
    float lv[8][4];
    for (int nt = 0; nt < 8; nt++)
        for (int r = 0; r < 4; r++)
            lv[nt][r] = bf2f(f2bf(sc[nt][r])) * 0.125f;

    int quad = l >> 4;
    __shared__ __align__(16) unsigned short att_s[64 * 136];
    for (int r = 0; r < 4; r++) {
        float mx = -1e30f;
        for (int nt = 0; nt < 8; nt++) mx = fmaxf(mx, lv[nt][r]);
        for (int off = 1; off < 16; off <<= 1) mx = fmaxf(mx, __shfl_xor(mx, off));
        float sm = 0.f;
        for (int nt = 0; nt < 8; nt++) { lv[nt][r] = expf(lv[nt][r] - mx); sm += lv[nt][r]; }
        for (int off = 1; off < 16; off <<= 1) sm += __shfl_xor(sm, off);
        float inv = 1.0f / sm;
        int row = w * 16 + quad * 4 + r;
        for (int nt = 0; nt < 8; nt++)
            att_s[row * 136 + nt * 16 + fr] = f2bf(lv[nt][r] * inv);
    }
    f32x4 o[4];
    for (int nt = 0; nt < 4; nt++) o[nt] = (f32x4){0.f, 0.f, 0.f, 0.f};
    for (int kt = 0; kt < 4; kt++) {
        s16x8 a = *(const s16x8*)&att_s[(w * 16 + fr) * 136 + kt * 32 + fq];
        const unsigned short* vb = (kt < 2) ? (vps + kt * 32 + fq)
                                            : (vpm + (kt - 2) * 32 + fq);
        for (int nt = 0; nt < 4; nt++) {
            s16x8 bv = *(const s16x8*)(vb + (nt * 16 + fr) * 64);
            o[nt] = __builtin_amdgcn_mfma_f32_16x16x32_bf16(a, bv, o[nt], 0, 0, 0);
        }
    }
    for (int nt = 0; nt < 4; nt++)
        for (int r = 0; r < 4; r++) {
            int m = w * 16 + quad * 4 + r;
            int d = nt * 16 + fr;
            g_enc[((size_t)b * 64 + m) * 1024 + h * 64 + d] =
                (_Float16)bf2f(f2bf(o[nt][r]));
        }
}

// out = enc @ wo.  grid = 16*16 = 256, block 256
__launch_bounds__(256)
__global__ void k_gemm2(int s) {
    int b = blockIdx.x >> 4, ntile = blockIdx.x & 15;
    if (!g_mask[b * 64 + s]) return;
    const _Float16* Abase = g_enc + (size_t)b * 64 * 1024;
    const _Float16* Bbase = g_Wot + (size_t)ntile * 64 * 1024;
    __shared__ __align__(16) _Float16 As[64 * 40];
    __shared__ __align__(16) _Float16 Bs[64 * 40];
    f32x4 acc[2][2] = {};
    gemm_core(Abase, Bbase, As, Bs, acc);

    int tid = threadIdx.x, w = tid >> 6, l = tid & 63;
    int mo = (w & 1) * 32, no = (w >> 1) * 32;
    int quad = l >> 4, col = l & 15;
    for (int i = 0; i < 2; i++)
        for (int j = 0; j < 2; j++)
            for (int r = 0; r < 4; r++) {
                int m = mo + i * 16 + quad * 4 + r;
                int n = ntile * 64 + no + j * 16 + col;
                g_outp[((size_t)b * 64 + m) * 1024 + n] = acc[i][j][r];
            }
}

// new_mem = LN_post(out+mem) in place; also h_mem = LN_pre(new_mem). grid=1024
__global__ void k_ln2(int s, float* __restrict__ dout,
                      const float* __restrict__ psc, const float* __restrict__ pbi,
                      const float* __restrict__ qsc, const float* __restrict__ qbi) {
    int b = blockIdx.x >> 6, r = blockIdx.x & 63;
    int t = threadIdx.x;
    size_t row = (size_t)b * 64 + r;
    if (!g_mask[b * 64 + s]) {
        if (s == NMs - 1)
            ((float4*)(dout + row * 1024))[t] = ((const float4*)(g_mem + row * 1024))[t];
        return;
    }
    float4 ov = ((const float4*)(g_outp + row * 1024))[t];
    float4 mv = ((const float4*)(g_mem + row * 1024))[t];
    float4 y = {ov.x + mv.x, ov.y + mv.y, ov.z + mv.z, ov.w + mv.w};
    float mean, rstd;
    block_stats(y.x + y.y + y.z + y.w,
                y.x * y.x + y.y * y.y + y.z * y.z + y.w * y.w, 1e-6f, &mean, &rstd);
    float4 s4 = ((const float4*)psc)[t];
    float4 b4 = ((const float4*)pbi)[t];
    float4 nm = {(y.x - mean) * rstd * s4.x + b4.x,
                 (y.y - mean) * rstd * s4.y + b4.y,
                 (y.z - mean) * rstd * s4.z + b4.z,
                 (y.w - mean) * rstd * s4.w + b4.w};
    ((float4*)(g_mem + row * 1024))[t] = nm;
    if (s == NMs - 1)
        ((float4*)(dout + row * 1024))[t] = nm;
    float m2, rs2;
    block_stats(nm.x + nm.y + nm.z + nm.w,
                nm.x * nm.x + nm.y * nm.y + nm.z * nm.z + nm.w * nm.w,
                1e-6f, &m2, &rs2);
    float4 c4 = ((const float4*)qsc)[t];
    float4 d4 = ((const float4*)qbi)[t];
    f16x4 o;
    o[0] = (_Float16)((nm.x - m2) * rs2 * c4.x + d4.x);
    o[1] = (_Float16)((nm.y - m2) * rs2 * c4.y + d4.y);
    o[2] = (_Float16)((nm.z - m2) * rs2 * c4.z + d4.z);
    o[3] = (_Float16)((nm.w - m2) * rs2 * c4.w + d4.w);
    *(f16x4*)(g_hmem + row * 1024 + t * 4) = o;
}

// ---------------------------------------------------------------------------
extern "C" void kernel_launch(void* const* d_in, const int* in_sizes, int n_in,
                              void* d_out, int out_size, void* d_ws, size_t ws_size,
                              hipStream_t stream) {
    (void)in_sizes; (void)n_in; (void)d_ws; (void)ws_size; (void)out_size;
    const float* hidden    = (const float*)d_in[0];
    const unsigned int* mk = (const unsigned int*)d_in[1];
    const float* mem_state = (const float*)d_in[2];
    const float* wq  = (const float*)d_in[3];
    const float* wk  = (const float*)d_in[4];
    const float* wv  = (const float*)d_in[5];
    const float* wo  = (const float*)d_in[6];
    const float* pre_s  = (const float*)d_in[7];
    const float* pre_b  = (const float*)d_in[8];
    const float* post_s = (const float*)d_in[9];
    const float* post_b = (const float*)d_in[10];
    float* out = (float*)d_out;

    k_transpose<<<dim3(16, 16), 256, 0, stream>>>(wq, 1024, 0);
    k_transpose<<<dim3(16, 8),  256, 0, stream>>>(wk, 512, 1);
    k_transpose<<<dim3(16, 8),  256, 0, stream>>>(wv, 512, 2);
    k_transpose<<<dim3(16, 16), 256, 0, stream>>>(wo, 1024, 3);
    k_rope<<<1, 128, 0, stream>>>();
    k_mask<<<1, 1024, 0, stream>>>(mk);
    k_ln_hx<<<NB * NMs * MBs, 256, 0, stream>>>(hidden, pre_s, pre_b);
    k_ln_init<<<NB * MEMm, 256, 0, stream>>>(mem_state, pre_s, pre_b);
    k_kv_big<<<4096, 256, 0, stream>>>();          // hoisted x-row K/V for all steps

    for (int s = 0; s < NMs; ++s) {
        k_gemm1<<<NB * 32, 256, 0, stream>>>(s);
        k_attn<<<NB * NHh, 256, 0, stream>>>(s);
        k_gemm2<<<NB * 16, 256, 0, stream>>>(s);
        k_ln2<<<NB * MEMm, 256, 0, stream>>>(s, out, post_s, post_b, pre_s, pre_b);
    }
}